// Round 9
// baseline (213.287 us; speedup 1.0000x reference)
//
#include <hip/hip_runtime.h>

#define LQ 768
#define DIN 256
#define DB 128
#define NH 8
#define DH 32

// ws float offsets
#define OFF_QB 0
#define OFF_KT (LQ*DIN)          // kT[DIN][LQ]  transposed, pre-scaled K
#define OFF_VB (2*LQ*DIN)
#define OFF_GB (3*LQ*DIN)
#define OFF_W2 (4*LQ*DIN)
#define OFF_SC (OFF_W2 + DB*NH)

// ---------------------------------------------------------------------------
// K1: proj (blocks 0..191, 4 rows each; K written transposed+scaled) +
//     setup (block 192: W2/S/C fold of the bias layernorm).
// ---------------------------------------------------------------------------
__global__ __launch_bounds__(256) void projsetup_kernel(
    const float* __restrict__ x, const float* __restrict__ lnw, const float* __restrict__ lnb,
    const float* __restrict__ Wq, const float* __restrict__ Wk, const float* __restrict__ Wv,
    const float* __restrict__ Wg, const float* __restrict__ bg,
    const float* __restrict__ lbw, const float* __restrict__ lbb, const float* __restrict__ Wb,
    float* __restrict__ qb, float* __restrict__ kT, float* __restrict__ vb, float* __restrict__ gb,
    float* __restrict__ W2, float* __restrict__ SC)
{
    const int tid = threadIdx.x;

    if (blockIdx.x == 192) {            // ---- setup ----
        if (tid < 128) {
            const int d = tid, lane = d & 63, wv = d >> 6;
            float w = lbw[d], b = lbb[d];
            float pS[NH], pC[NH];
            #pragma unroll
            for (int h = 0; h < NH; h++) {
                float wb = Wb[d*NH + h];
                float w2 = w * wb;
                W2[d*NH + h] = w2;
                pS[h] = w2;
                pC[h] = b * wb;
            }
            #pragma unroll
            for (int m = 1; m <= 32; m <<= 1) {
                #pragma unroll
                for (int h = 0; h < NH; h++) { pS[h] += __shfl_xor(pS[h], m); pC[h] += __shfl_xor(pC[h], m); }
            }
            __shared__ float red[2][16];
            if (lane == 0) {
                #pragma unroll
                for (int h = 0; h < NH; h++) { red[wv][h] = pS[h]; red[wv][NH+h] = pC[h]; }
            }
            __syncthreads();
            if (d < 16) SC[d] = red[0][d] + red[1][d];
        }
        return;
    }

    // ---- proj: 4 rows per block ----
    const int lane = tid & 63, rr = tid >> 6;
    const int row = blockIdx.x * 4 + rr;
    __shared__ float xn[4][DIN];

    float4 xv = ((const float4*)x)[row * (DIN/4) + lane];
    float s  = xv.x + xv.y + xv.z + xv.w;
    float ss = xv.x*xv.x + xv.y*xv.y + xv.z*xv.z + xv.w*xv.w;
    #pragma unroll
    for (int m = 1; m <= 32; m <<= 1) { s += __shfl_xor(s, m); ss += __shfl_xor(ss, m); }
    float mu  = s * (1.0f/DIN);
    float inv = rsqrtf(ss * (1.0f/DIN) - mu*mu + 1e-5f);
    float4 wv4 = ((const float4*)lnw)[lane];
    float4 bv4 = ((const float4*)lnb)[lane];
    float4 r4;
    r4.x = (xv.x - mu)*inv*wv4.x + bv4.x;
    r4.y = (xv.y - mu)*inv*wv4.y + bv4.y;
    r4.z = (xv.z - mu)*inv*wv4.z + bv4.z;
    r4.w = (xv.w - mu)*inv*wv4.w + bv4.w;
    *((float4*)&xn[rr][lane*4]) = r4;
    __syncthreads();

    const int col = tid;
    float aq[4] = {0,0,0,0}, ak[4] = {0,0,0,0}, av[4] = {0,0,0,0}, ag[4] = {0,0,0,0};
    for (int i4 = 0; i4 < DIN/4; i4++) {
        float4 x0 = *((const float4*)&xn[0][i4*4]);
        float4 x1 = *((const float4*)&xn[1][i4*4]);
        float4 x2 = *((const float4*)&xn[2][i4*4]);
        float4 x3 = *((const float4*)&xn[3][i4*4]);
        const float* p0 = (const float*)&x0;
        const float* p1 = (const float*)&x1;
        const float* p2 = (const float*)&x2;
        const float* p3 = (const float*)&x3;
        #pragma unroll
        for (int e = 0; e < 4; e++) {
            const int i = i4*4 + e;
            float wq = Wq[i*DIN + col], wk = Wk[i*DIN + col];
            float wvv = Wv[i*DIN + col], wg = Wg[i*DIN + col];
            aq[0] = fmaf(p0[e], wq, aq[0]); aq[1] = fmaf(p1[e], wq, aq[1]);
            aq[2] = fmaf(p2[e], wq, aq[2]); aq[3] = fmaf(p3[e], wq, aq[3]);
            ak[0] = fmaf(p0[e], wk, ak[0]); ak[1] = fmaf(p1[e], wk, ak[1]);
            ak[2] = fmaf(p2[e], wk, ak[2]); ak[3] = fmaf(p3[e], wk, ak[3]);
            av[0] = fmaf(p0[e], wvv, av[0]); av[1] = fmaf(p1[e], wvv, av[1]);
            av[2] = fmaf(p2[e], wvv, av[2]); av[3] = fmaf(p3[e], wvv, av[3]);
            ag[0] = fmaf(p0[e], wg, ag[0]); ag[1] = fmaf(p1[e], wg, ag[1]);
            ag[2] = fmaf(p2[e], wg, ag[2]); ag[3] = fmaf(p3[e], wg, ag[3]);
        }
    }
    const float kscale = 0.17677669529663687f;  // 1/sqrt(DH)
    float bgv = bg[col];
    #pragma unroll
    for (int r = 0; r < 4; r++) {
        const int orow = blockIdx.x*4 + r;
        qb[orow*DIN + col] = aq[r];
        vb[orow*DIN + col] = av[r];
        gb[orow*DIN + col] = 1.0f/(1.0f + __expf(-(ag[r] + bgv)));
    }
    *((float4*)&kT[col*LQ + blockIdx.x*4]) =
        make_float4(ak[0]*kscale, ak[1]*kscale, ak[2]*kscale, ak[3]*kscale);
}

// ---------------------------------------------------------------------------
// K2: mega per-q kernel. 768 blocks x 256 threads (4 waves), 2 blocks/CU.
// Prologue: issue tile0 reg-loads -> qk from kT into pT (hides HBM latency)
//           -> barrier.
// Stream:   each wave owns 192 keys = 12 tiles of 16 keys x 128 dims (8KB).
//           T14 reg-staged single-buffer pipeline: v[8] holds tile t+1 in
//           flight while scanning tile t from LDS. R5's proven swizzle:
//           content at LDS addr A is global (A ^ key-bits), read addr
//           rbase0^(j<<4) -> minimum bank conflicts; w2p broadcast slabs.
// Tail:     softmax, PV (unnormalized p, scale at end), gate, Wo in-block.
// ---------------------------------------------------------------------------
__global__ __launch_bounds__(256) void mega_kernel(
    const float* __restrict__ bias, const float* __restrict__ W2g,
    const float* __restrict__ SCg, const float* __restrict__ qbuf,
    const float* __restrict__ kT, const float* __restrict__ vbuf,
    const float* __restrict__ gbuf, const float* __restrict__ Wo,
    const float* __restrict__ bo, float* __restrict__ out)
{
    __shared__ float tiles[4][2048];    // 8KB per wave (single buffer)
    __shared__ float w2p[4*264];        // 4 q4-slabs, stride 264
    __shared__ float pT[NH][776];
    __shared__ float ao[DIN];
    __shared__ float isum[NH];

    const int tid  = threadIdx.x;
    const int q    = blockIdx.x;
    const int w    = tid >> 6;
    const int lane = tid & 63;
    const int key  = lane & 15;
    const int q4   = lane >> 4;

    const char* gwave = (const char*)bias + ((size_t)q*LQ + w*192) * (DB*4);
    float* tw = &tiles[w][0];

    // per-lane source offset with the involution swizzle (bits 4..7 ^= key)
    int soff[8];
    #pragma unroll
    for (int c = 0; c < 8; c++) {
        int L = c*1024 + lane*16;
        soff[c] = L ^ (((L >> 9) & 15) << 4);
    }

    float4 v[8];
    // issue tile 0 loads (fly during w2p fill + qk)
    #pragma unroll
    for (int c = 0; c < 8; c++) v[c] = *(const float4*)(gwave + soff[c]);

    // w2p fill
    for (int j = tid; j < 4*264; j += 256) {
        int g = j / 264, rem = j - g*264;
        w2p[j] = (rem < 256) ? W2g[g*256 + rem] : 0.0f;
    }

    // qk prologue: 192 threads, 4 keys each, all 8 heads -> pT
    if (tid < 192) {
        float acc[4][NH];
        #pragma unroll
        for (int e = 0; e < 4; e++)
            #pragma unroll
            for (int h = 0; h < NH; h++) acc[e][h] = 0.f;
        const float* qp = qbuf + (size_t)q*DIN;          // uniform -> s_load
        #pragma unroll
        for (int h = 0; h < NH; h++) {
            #pragma unroll
            for (int dd = 0; dd < DH; dd++) {
                const int d = h*DH + dd;
                float4 kv = *(const float4*)(kT + (size_t)d*LQ + tid*4);
                float qa = qp[d];
                acc[0][h] = fmaf(qa, kv.x, acc[0][h]);
                acc[1][h] = fmaf(qa, kv.y, acc[1][h]);
                acc[2][h] = fmaf(qa, kv.z, acc[2][h]);
                acc[3][h] = fmaf(qa, kv.w, acc[3][h]);
            }
        }
        #pragma unroll
        for (int h = 0; h < NH; h++)
            *(float4*)&pT[h][tid*4] = make_float4(acc[0][h], acc[1][h], acc[2][h], acc[3][h]);
    }

    asm volatile("s_waitcnt lgkmcnt(0)" ::: "memory");
    __builtin_amdgcn_s_barrier();
    asm volatile("" ::: "memory");

    float Sh[NH], Ch[NH];
    #pragma unroll
    for (int h = 0; h < NH; h++) { Sh[h] = SCg[h]; Ch[h] = SCg[NH + h]; }

    // write tile0 (auto-waits v), issue tile1 loads
    #pragma unroll
    for (int c = 0; c < 8; c++) *(float4*)((char*)tw + c*1024 + lane*16) = v[c];
    #pragma unroll
    for (int c = 0; c < 8; c++) v[c] = *(const float4*)(gwave + 8192 + soff[c]);

    const int rbase0 = ((key << 9) | (q4 << 7)) ^ (key << 4);
    const float* wp = &w2p[q4*264];

    #pragma unroll
    for (int t = 0; t < 12; t++) {
        // ---- scan tile t ----
        float s = 0.f, ss = 0.f;
        float acc[NH] = {0,0,0,0,0,0,0,0};
        #pragma unroll
        for (int j = 0; j < 8; j++) {
            float4 bv = *(const float4*)((const char*)tw + (rbase0 ^ (j << 4)));
            const float* wj = wp + j*32;
            #pragma unroll
            for (int e = 0; e < 4; e++) {
                float xv = (&bv.x)[e];
                s += xv; ss = fmaf(xv, xv, ss);
                float4 w0 = *(const float4*)(wj + e*8);
                float4 w1 = *(const float4*)(wj + e*8 + 4);
                acc[0] = fmaf(xv, w0.x, acc[0]); acc[1] = fmaf(xv, w0.y, acc[1]);
                acc[2] = fmaf(xv, w0.z, acc[2]); acc[3] = fmaf(xv, w0.w, acc[3]);
                acc[4] = fmaf(xv, w1.x, acc[4]); acc[5] = fmaf(xv, w1.y, acc[5]);
                acc[6] = fmaf(xv, w1.z, acc[6]); acc[7] = fmaf(xv, w1.w, acc[7]);
            }
        }
        #pragma unroll
        for (int m = 16; m <= 32; m <<= 1) {
            s += __shfl_xor(s, m); ss += __shfl_xor(ss, m);
            #pragma unroll
            for (int h = 0; h < NH; h++) acc[h] += __shfl_xor(acc[h], m);
        }
        if (q4 == 0) {
            float mu  = s * (1.0f/DB);
            float inv = rsqrtf(ss * (1.0f/DB) - mu*mu + 1e-5f);
            const int k = w*192 + t*16 + key;
            #pragma unroll
            for (int h = 0; h < NH; h++)
                pT[h][k] += fmaf(inv, fmaf(-mu, Sh[h], acc[h]), Ch[h]);
        }

        // ---- rotate pipeline: write tile t+1, issue tile t+2 ----
        if (t < 11) {
            asm volatile("s_waitcnt lgkmcnt(0)" ::: "memory");   // scan reads done
            #pragma unroll
            for (int c = 0; c < 8; c++) *(float4*)((char*)tw + c*1024 + lane*16) = v[c];
            if (t < 10) {
                const char* gs = gwave + (size_t)(t + 2)*8192;
                #pragma unroll
                for (int c = 0; c < 8; c++) v[c] = *(const float4*)(gs + soff[c]);
            }
        }
    }

    asm volatile("s_waitcnt lgkmcnt(0)" ::: "memory");
    __builtin_amdgcn_s_barrier();
    asm volatile("" ::: "memory");

    // ---- softmax over keys per head ----
    {
        const int h = tid >> 5, l = tid & 31;
        float m = -1e30f;
        for (int i = l; i < LQ; i += 32) m = fmaxf(m, pT[h][i]);
        #pragma unroll
        for (int mm = 1; mm <= 16; mm <<= 1) m = fmaxf(m, __shfl_xor(m, mm));
        float sum = 0.f;
        for (int i = l; i < LQ; i += 32) {
            float e = __expf(pT[h][i] - m);
            pT[h][i] = e;
            sum += e;
        }
        #pragma unroll
        for (int mm = 1; mm <= 16; mm <<= 1) sum += __shfl_xor(sum, mm);
        if (l == 0) isum[h] = 1.0f / sum;
    }
    __syncthreads();

    // ---- PV + gate ----
    {
        const int h = tid >> 5, d = tid & 31;
        const float* vp = vbuf + h*DH + d;
        float a = 0.f;
        for (int k4 = 0; k4 < LQ/4; k4++) {
            float4 p = *(const float4*)&pT[h][k4*4];     // broadcast
            a = fmaf(p.x, vp[(size_t)(k4*4+0)*DIN], a);
            a = fmaf(p.y, vp[(size_t)(k4*4+1)*DIN], a);
            a = fmaf(p.z, vp[(size_t)(k4*4+2)*DIN], a);
            a = fmaf(p.w, vp[(size_t)(k4*4+3)*DIN], a);
        }
        ao[tid] = a * isum[h] * gbuf[(size_t)q*DIN + tid];
    }
    __syncthreads();

    // ---- output projection ----
    {
        float o = bo[tid];
        for (int i = 0; i < DIN; i++) o = fmaf(ao[i], Wo[i*DIN + tid], o);
        out[(size_t)q*DIN + tid] = o;
    }
}

extern "C" void kernel_launch(void* const* d_in, const int* in_sizes, int n_in,
                              void* d_out, int out_size, void* d_ws, size_t ws_size,
                              hipStream_t stream) {
    const float* x    = (const float*)d_in[0];
    const float* bias = (const float*)d_in[1];
    const float* lnw  = (const float*)d_in[2];
    const float* lnb  = (const float*)d_in[3];
    const float* lbw  = (const float*)d_in[4];
    const float* lbb  = (const float*)d_in[5];
    const float* Wq   = (const float*)d_in[6];
    const float* Wk   = (const float*)d_in[7];
    const float* Wv   = (const float*)d_in[8];
    const float* Wb   = (const float*)d_in[9];
    const float* Wg   = (const float*)d_in[10];
    const float* bg   = (const float*)d_in[11];
    const float* Wo   = (const float*)d_in[12];
    const float* bo   = (const float*)d_in[13];

    float* ws = (float*)d_ws;
    float* qb = ws + OFF_QB;
    float* kT = ws + OFF_KT;
    float* vb = ws + OFF_VB;
    float* gb = ws + OFF_GB;
    float* W2 = ws + OFF_W2;
    float* SC = ws + OFF_SC;

    projsetup_kernel<<<193, 256, 0, stream>>>(x, lnw, lnb, Wq, Wk, Wv, Wg, bg,
                                              lbw, lbb, Wb, qb, kT, vb, gb, W2, SC);
    mega_kernel<<<LQ, 256, 0, stream>>>(bias, W2, SC, qb, kT, vb, gb, Wo, bo, (float*)d_out);
}